// Round 2
// baseline (93.607 us; speedup 1.0000x reference)
//
#include <hip/hip_runtime.h>

// loss = sum_{i: yt=1, j: yt=0} max(0, 1 - yp_i + yp_j) / (n_pos * n_neg)
// N = 32*512 = 16384.
//
// Round 2 design:
//   A) compact_kernel (1 block): compacts c_i = 1 - yp_i (pos) and q_j = yp_j
//      (neg) into ws via LDS-atomic offset reservation (order irrelevant for a
//      sum). Writes {npos, nneg} header. No global zero-init needed anywhere.
//   B) pair_kernel (64 x 16 blocks, TJ=1024): brute hinge over compacted
//      npos x nneg (~67M pairs, 4x less than 268M slots). Sentinel -1e30 for
//      pad lanes -> term clamps to 0. Each block writes its partial to a
//      DISTINCT ws slot (written unconditionally -> no init, no atomics).
//   C) finalize (1 block): sums 1024 partials, divides by npos*nneg.
// No hipMemsetAsync: R1 trace showed our 4-byte fill dispatch costing ~39us.

#define N_TOTAL 16384
#define TJ 1024
#define BLOCK 256
#define GX 64            // ceil(N_TOTAL/BLOCK) worst case
#define GY 16            // ceil(N_TOTAL/TJ) worst case
#define NPART (GX * GY)

// ws layout (bytes):
//   0:   uint npos
//   4:   uint nneg
//   64:  float cs[16384]
//   64 + 65536:  float qs[16384]
//   64 + 131072: float partials[NPART]
#define CS_OFF 64
#define QS_OFF (64 + 65536)
#define PART_OFF (64 + 131072)

__global__ void __launch_bounds__(BLOCK) compact_kernel(
    const int* __restrict__ yt, const float* __restrict__ yp,
    unsigned char* __restrict__ ws) {
  __shared__ unsigned ctr[2];
  const int tid = threadIdx.x;
  if (tid < 2) ctr[tid] = 0;
  __syncthreads();

  unsigned* hdr = (unsigned*)ws;
  float* cs = (float*)(ws + CS_OFF);
  float* qs = (float*)(ws + QS_OFF);

  const int base = tid * 64;  // 256 threads x 64 elems = 16384

  // pass 1: count positives in my chunk
  int pc = 0;
#pragma unroll
  for (int k = 0; k < 64; k += 4) {
    int4 t = *(const int4*)(yt + base + k);
    pc += (t.x == 1) + (t.y == 1) + (t.z == 1) + (t.w == 1);
  }
  unsigned pb = atomicAdd(&ctr[0], (unsigned)pc);
  unsigned nb = atomicAdd(&ctr[1], (unsigned)(64 - pc));

  // pass 2: write compacted values
#pragma unroll 4
  for (int k = 0; k < 64; k += 4) {
    int4 t = *(const int4*)(yt + base + k);
    float4 p = *(const float4*)(yp + base + k);
    if (t.x == 1) cs[pb++] = 1.0f - p.x; else qs[nb++] = p.x;
    if (t.y == 1) cs[pb++] = 1.0f - p.y; else qs[nb++] = p.y;
    if (t.z == 1) cs[pb++] = 1.0f - p.z; else qs[nb++] = p.z;
    if (t.w == 1) cs[pb++] = 1.0f - p.w; else qs[nb++] = p.w;
  }
  __syncthreads();
  if (tid == 0) { hdr[0] = ctr[0]; hdr[1] = ctr[1]; }
}

__global__ void __launch_bounds__(BLOCK) pair_kernel(
    unsigned char* __restrict__ ws) {
  const unsigned* hdr = (const unsigned*)ws;
  const int npos = (int)hdr[0];
  const int nneg = (int)hdr[1];
  const float* cs = (const float*)(ws + CS_OFF);
  const float* qs = (const float*)(ws + QS_OFF);
  float* partials = (float*)(ws + PART_OFF);

  const int tid = threadIdx.x;
  const int bx = blockIdx.x, by = blockIdx.y;
  const int lin = by * GX + bx;
  const int i = bx * BLOCK + tid;
  const int j0 = by * TJ;

  float sum = 0.0f;
  __shared__ float qsh[TJ];
  if (bx * BLOCK < npos && j0 < nneg) {  // block-uniform skip
    // stage j tile (bounds-checked, pad with sentinel)
    for (int k = tid; k < TJ; k += BLOCK) {
      int j = j0 + k;
      qsh[k] = (j < nneg) ? qs[j] : -1e30f;
    }
    const float c = (i < npos) ? cs[i] : -1e30f;
    __syncthreads();

    float a0 = 0.f, a1 = 0.f, a2 = 0.f, a3 = 0.f;
#pragma unroll 4
    for (int jj = 0; jj < TJ; jj += 4) {
      float4 q = *(const float4*)(qsh + jj);  // wave-uniform -> LDS broadcast
      a0 += fmaxf(0.f, c + q.x);
      a1 += fmaxf(0.f, c + q.y);
      a2 += fmaxf(0.f, c + q.z);
      a3 += fmaxf(0.f, c + q.w);
    }
    sum = (a0 + a1) + (a2 + a3);
  }

  // block reduction (all threads reach here; skipped blocks contribute 0)
#pragma unroll
  for (int off = 32; off > 0; off >>= 1) sum += __shfl_down(sum, off, 64);
  __shared__ float wsum[BLOCK / 64];
  if ((tid & 63) == 0) wsum[tid >> 6] = sum;
  __syncthreads();
  if (tid == 0)
    partials[lin] = (wsum[0] + wsum[1]) + (wsum[2] + wsum[3]);
}

__global__ void __launch_bounds__(BLOCK) finalize_kernel(
    const unsigned char* __restrict__ ws, float* __restrict__ out) {
  const unsigned* hdr = (const unsigned*)ws;
  const float* partials = (const float*)(ws + PART_OFF);
  const int tid = threadIdx.x;

  float s = 0.f;
#pragma unroll
  for (int k = tid; k < NPART; k += BLOCK) s += partials[k];
#pragma unroll
  for (int off = 32; off > 0; off >>= 1) s += __shfl_down(s, off, 64);

  __shared__ float wsum[BLOCK / 64];
  if ((tid & 63) == 0) wsum[tid >> 6] = s;
  __syncthreads();
  if (tid == 0) {
    float num = (wsum[0] + wsum[1]) + (wsum[2] + wsum[3]);
    float denom = (float)hdr[0] * (float)hdr[1];
    out[0] = num / denom;
  }
}

extern "C" void kernel_launch(void* const* d_in, const int* in_sizes, int n_in,
                              void* d_out, int out_size, void* d_ws,
                              size_t ws_size, hipStream_t stream) {
  const int* yt = (const int*)d_in[0];     // y_true, int32, 16384
  const float* yp = (const float*)d_in[1]; // y_pred, float32, 16384
  float* out = (float*)d_out;
  unsigned char* ws = (unsigned char*)d_ws;

  compact_kernel<<<1, BLOCK, 0, stream>>>(yt, yp, ws);
  pair_kernel<<<dim3(GX, GY), BLOCK, 0, stream>>>(ws);
  finalize_kernel<<<1, BLOCK, 0, stream>>>(ws, out);
}